// Round 1
// baseline (8071.048 us; speedup 1.0000x reference)
//
#include <hip/hip_runtime.h>

// NeighborhoodTransformer: N=20000 nodes, K=32 tokens, D=256, H=8 heads (dh=32), L=3 layers.
// One block (512 thr, 8 waves) per node; fully fused in LDS; bf16 MFMA 16x16x32.

#define TOK 32
#define DIM 256
#define NHEAD 8
#define NLAYER 3
#define SCALE 0.17677669529663687f  // 1/sqrt(32)

typedef __bf16 bf16;
typedef __bf16 bf16x8 __attribute__((ext_vector_type(8)));
typedef __bf16 bf16x4 __attribute__((ext_vector_type(4)));
typedef float f32x4 __attribute__((ext_vector_type(4)));

#define MFMA(a, b, c) __builtin_amdgcn_mfma_f32_16x16x32_bf16(a, b, c, 0, 0, 0)

// weight segment offsets inside d_ws (bf16 elems)
#define OFF_WQKV 0
#define OFF_WO   589824   // 3*768*256
#define OFF_W1   786432
#define OFF_W2   983040
#define WTOT     1179648

__device__ __forceinline__ float wred_max16(float v) {
  v = fmaxf(v, __shfl_xor(v, 1)); v = fmaxf(v, __shfl_xor(v, 2));
  v = fmaxf(v, __shfl_xor(v, 4)); v = fmaxf(v, __shfl_xor(v, 8));
  return v;
}
__device__ __forceinline__ float wred_sum16(float v) {
  v += __shfl_xor(v, 1); v += __shfl_xor(v, 2);
  v += __shfl_xor(v, 4); v += __shfl_xor(v, 8);
  return v;
}

// GEMM: out[t][o] = sum_d A[t][d] * W[o][d].  A from LDS (fp32 row-stride 260, or bf16
// row-stride 264), W bf16 global row-major [o][256]. Wave computes M-tiles {0,16} x NT
// N-tiles at obase. qlim>0: N-tiles with o<qlim compute only M-tile 0 (last-layer Q).
// mtiles==1: only M-tile 0 everywhere (last-layer out-proj/FF).
template <bool AF32, int NT>
__device__ __forceinline__ void gemm_run(const float* Af, const bf16* Ab,
                                         const bf16* __restrict__ W, int obase,
                                         int quad, int lc, int mtiles, int qlim,
                                         f32x4 (&acc)[2][NT]) {
#pragma unroll
  for (int m = 0; m < 2; m++)
#pragma unroll
    for (int j = 0; j < NT; j++) acc[m][j] = (f32x4){0.f, 0.f, 0.f, 0.f};

  auto loadA = [&](int m0, int k0) -> bf16x8 {
    const int row = m0 + lc;
    const int col = k0 + quad * 8;
    if constexpr (AF32) {
      const f32x4* p = (const f32x4*)(Af + row * 260 + col);
      f32x4 x0 = p[0];
      f32x4 x1 = p[1];
      bf16x8 r;
      r[0] = (bf16)x0[0]; r[1] = (bf16)x0[1]; r[2] = (bf16)x0[2]; r[3] = (bf16)x0[3];
      r[4] = (bf16)x1[0]; r[5] = (bf16)x1[1]; r[6] = (bf16)x1[2]; r[7] = (bf16)x1[3];
      return r;
    } else {
      return *(const bf16x8*)(Ab + row * 264 + col);
    }
  };
  auto loadB = [&](int j, int k0) -> bf16x8 {
    return *(const bf16x8*)(W + (obase + j * 16 + lc) * DIM + k0 + quad * 8);
  };

  bf16x8 a0 = loadA(0, 0);
  bf16x8 a1 = loadA(16, 0);
  bf16x8 b[NT];
#pragma unroll
  for (int j = 0; j < NT; j++) b[j] = loadB(j, 0);

#pragma unroll
  for (int ks = 0; ks < 8; ks++) {
    bf16x8 na0, na1, nb[NT];
    if (ks < 7) {  // 1-deep prefetch of next K-step
      na0 = loadA(0, (ks + 1) * 32);
      na1 = loadA(16, (ks + 1) * 32);
#pragma unroll
      for (int j = 0; j < NT; j++) nb[j] = loadB(j, (ks + 1) * 32);
    }
#pragma unroll
    for (int j = 0; j < NT; j++) {
      acc[0][j] = MFMA(a0, b[j], acc[0][j]);
      if (mtiles > 1 && (qlim == 0 || (obase + j * 16) >= qlim))
        acc[1][j] = MFMA(a1, b[j], acc[1][j]);
    }
    a0 = na0; a1 = na1;
#pragma unroll
    for (int j = 0; j < NT; j++) b[j] = nb[j];
  }
}

__device__ __forceinline__ void lnorm(float (*xf)[260], const float* __restrict__ g,
                                      const float* __restrict__ b, int tid) {
  const int t = tid >> 4, i = tid & 15;  // 16 threads per row
  float v[16];
  float s = 0.f;
#pragma unroll
  for (int j = 0; j < 16; j++) { v[j] = xf[t][i + 16 * j]; s += v[j]; }
  s = wred_sum16(s);
  const float mu = s * (1.f / 256.f);
  float q = 0.f;
#pragma unroll
  for (int j = 0; j < 16; j++) { const float d = v[j] - mu; q += d * d; }
  q = wred_sum16(q);
  const float inv = rsqrtf(q * (1.f / 256.f) + 1e-5f);
#pragma unroll
  for (int j = 0; j < 16; j++) {
    const int d = i + 16 * j;
    xf[t][d] = (v[j] - mu) * inv * g[d] + b[d];
  }
}

// fp32 -> bf16 weight conversion into workspace (rerun every call: ws is re-poisoned)
__global__ __launch_bounds__(256) void cvtw(const float* __restrict__ wq,
                                            const float* __restrict__ wo,
                                            const float* __restrict__ w1,
                                            const float* __restrict__ w2,
                                            bf16* __restrict__ ws) {
  const int i = (blockIdx.x * 256 + threadIdx.x) * 4;  // 1152*256*4 == WTOT exactly
  float4 v;
  if (i < OFF_WO)       v = *(const float4*)(wq + i);
  else if (i < OFF_W1)  v = *(const float4*)(wo + (i - OFF_WO));
  else if (i < OFF_W2)  v = *(const float4*)(w1 + (i - OFF_W1));
  else                  v = *(const float4*)(w2 + (i - OFF_W2));
  bf16x4 r;
  r[0] = (bf16)v.x; r[1] = (bf16)v.y; r[2] = (bf16)v.z; r[3] = (bf16)v.w;
  *(bf16x4*)(ws + i) = r;
}

__global__ __launch_bounds__(512, 2) void nt_fused(
    const float* __restrict__ h, const float* __restrict__ e, const int* __restrict__ src,
    const bf16* __restrict__ wall, const float* __restrict__ inb,
    const float* __restrict__ outbias, const float* __restrict__ f1b,
    const float* __restrict__ f2b, const float* __restrict__ l1g,
    const float* __restrict__ l1b, const float* __restrict__ l2g,
    const float* __restrict__ l2b, float* __restrict__ out) {
  __shared__ float xf[TOK][260];      // master x, fp32 (pad 260 -> stride 1040B, 16B-aligned)
  __shared__ bf16 qb[TOK][264];       // Q
  __shared__ bf16 kb[TOK][264];       // K
  __shared__ bf16 vt[DIM][40];        // V transposed: vt[c][u]
  __shared__ bf16 ob[TOK][264];       // attn out, reused as FF mid
  __shared__ bf16 pb[NHEAD][TOK][40]; // per-head softmax P

  const int node = blockIdx.x;
  const int tid = threadIdx.x;
  const int wave = tid >> 6;
  const int lane = tid & 63;
  const int quad = lane >> 4;
  const int lc = lane & 15;

  // stage x = h[src] + e  (16 threads per token row, 16 floats each)
  {
    const int t = tid >> 4;
    const int i = tid & 15;
    const int s = src[node * TOK + t];
    const float* hp = h + (size_t)s * DIM + i * 16;
    const float* ep = e + ((size_t)node * TOK + t) * DIM + i * 16;
#pragma unroll
    for (int j = 0; j < 4; j++) {
      const f32x4 hv = *(const f32x4*)(hp + 4 * j);
      const f32x4 ev = *(const f32x4*)(ep + 4 * j);
      *(f32x4*)&xf[t][i * 16 + 4 * j] = hv + ev;
    }
  }
  __syncthreads();

#pragma unroll 1
  for (int layer = 0; layer < NLAYER; layer++) {
    const bool lastl = (layer == NLAYER - 1);  // only token 0 needed downstream
    const bf16* Wq = wall + OFF_WQKV + layer * (768 * 256);
    const bf16* Wo = wall + OFF_WO + layer * 65536;
    const bf16* W1 = wall + OFF_W1 + layer * 65536;
    const bf16* W2 = wall + OFF_W2 + layer * 65536;
    const float* bq = inb + layer * 768;
    const float* bo = outbias + layer * 256;
    const float* b1 = f1b + layer * 256;
    const float* b2 = f2b + layer * 256;
    const float* g1 = l1g + layer * 256;
    const float* be1 = l1b + layer * 256;
    const float* g2 = l2g + layer * 256;
    const float* be2 = l2b + layer * 256;

    // ---- QKV projection: wave owns o in [wave*96, wave*96+96)
    {
      f32x4 acc[2][6];
      gemm_run<true, 6>(&xf[0][0], nullptr, Wq, wave * 96, quad, lc, 2,
                        lastl ? 256 : 0, acc);
#pragma unroll
      for (int j = 0; j < 6; j++) {
        const int o = wave * 96 + j * 16 + lc;
        const float bias = bq[o];
#pragma unroll
        for (int m = 0; m < 2; m++) {
#pragma unroll
          for (int r = 0; r < 4; r++) {
            const int t = m * 16 + quad * 4 + r;
            const float v = acc[m][j][r] + bias;
            if (o < 256)      qb[t][o] = (bf16)v;
            else if (o < 512) kb[t][o - 256] = (bf16)v;
            else              vt[o - 512][t] = (bf16)v;   // V stored transposed
          }
        }
      }
    }
    __syncthreads();

    // ---- attention: one head per wave
    {
      const int hh = wave;
      const int nT = lastl ? 1 : 2;  // last layer: only query rows 0..15 (row 0 needed)
      const f32x4 z4 = {0.f, 0.f, 0.f, 0.f};
      bf16x8 aq[2], bk[2];
#pragma unroll
      for (int ti = 0; ti < 2; ti++)
        if (ti < nT) aq[ti] = *(const bf16x8*)&qb[ti * 16 + lc][hh * 32 + quad * 8];
#pragma unroll
      for (int ui = 0; ui < 2; ui++)
        bk[ui] = *(const bf16x8*)&kb[ui * 16 + lc][hh * 32 + quad * 8];
      f32x4 sA[2][2];
#pragma unroll
      for (int ti = 0; ti < 2; ti++)
        if (ti < nT) {
          sA[ti][0] = MFMA(aq[ti], bk[0], z4);
          sA[ti][1] = MFMA(aq[ti], bk[1], z4);
        }
      // softmax over u (rows split across 16 lanes x 2 u-tiles), write P to LDS (bf16)
#pragma unroll
      for (int ti = 0; ti < 2; ti++)
        if (ti < nT) {
#pragma unroll
          for (int r = 0; r < 4; r++) {
            float p0 = sA[ti][0][r] * SCALE;
            float p1 = sA[ti][1][r] * SCALE;
            const float mx = wred_max16(fmaxf(p0, p1));
            p0 = __expf(p0 - mx);
            p1 = __expf(p1 - mx);
            const float rs = 1.f / wred_sum16(p0 + p1);
            const int t = ti * 16 + quad * 4 + r;
            pb[hh][t][lc] = (bf16)(p0 * rs);
            pb[hh][t][16 + lc] = (bf16)(p1 * rs);
          }
        }
      // O = P @ V  (P via LDS round-trip into A-layout; V read from vt as B-operand)
      bf16x8 ap[2], bv[2];
#pragma unroll
      for (int ti = 0; ti < 2; ti++)
        if (ti < nT) ap[ti] = *(const bf16x8*)&pb[hh][ti * 16 + lc][quad * 8];
#pragma unroll
      for (int ci = 0; ci < 2; ci++)
        bv[ci] = *(const bf16x8*)&vt[hh * 32 + ci * 16 + lc][quad * 8];
#pragma unroll
      for (int ti = 0; ti < 2; ti++)
        if (ti < nT) {
#pragma unroll
          for (int ci = 0; ci < 2; ci++) {
            const f32x4 oo = MFMA(ap[ti], bv[ci], z4);
#pragma unroll
            for (int r = 0; r < 4; r++)
              ob[ti * 16 + quad * 4 + r][hh * 32 + ci * 16 + lc] = (bf16)oo[r];
          }
        }
    }
    __syncthreads();

    // ---- out projection (+residual into xf): wave owns o in [wave*32, wave*32+32)
    {
      const int mt = lastl ? 1 : 2;
      f32x4 acc[2][2];
      gemm_run<false, 2>(nullptr, &ob[0][0], Wo, wave * 32, quad, lc, mt, 0, acc);
#pragma unroll
      for (int j = 0; j < 2; j++) {
        const int o = wave * 32 + j * 16 + lc;
        const float bias = bo[o];
#pragma unroll
        for (int m = 0; m < 2; m++)
          if (m < mt) {
#pragma unroll
            for (int r = 0; r < 4; r++) {
              const int t = m * 16 + quad * 4 + r;
              xf[t][o] += acc[m][j][r] + bias;
            }
          }
      }
    }
    __syncthreads();
    lnorm(xf, g1, be1, tid);
    __syncthreads();

    // ---- FF1 (relu) -> ob
    {
      const int mt = lastl ? 1 : 2;
      f32x4 acc[2][2];
      gemm_run<true, 2>(&xf[0][0], nullptr, W1, wave * 32, quad, lc, mt, 0, acc);
#pragma unroll
      for (int j = 0; j < 2; j++) {
        const int o = wave * 32 + j * 16 + lc;
        const float bias = b1[o];
#pragma unroll
        for (int m = 0; m < 2; m++)
          if (m < mt) {
#pragma unroll
            for (int r = 0; r < 4; r++) {
              const int t = m * 16 + quad * 4 + r;
              ob[t][o] = (bf16)fmaxf(acc[m][j][r] + bias, 0.f);
            }
          }
      }
    }
    __syncthreads();

    // ---- FF2 (+residual into xf)
    {
      const int mt = lastl ? 1 : 2;
      f32x4 acc[2][2];
      gemm_run<false, 2>(nullptr, &ob[0][0], W2, wave * 32, quad, lc, mt, 0, acc);
#pragma unroll
      for (int j = 0; j < 2; j++) {
        const int o = wave * 32 + j * 16 + lc;
        const float bias = b2[o];
#pragma unroll
        for (int m = 0; m < 2; m++)
          if (m < mt) {
#pragma unroll
            for (int r = 0; r < 4; r++) {
              const int t = m * 16 + quad * 4 + r;
              xf[t][o] += acc[m][j][r] + bias;
            }
          }
      }
    }
    __syncthreads();
    lnorm(xf, g2, be2, tid);
    __syncthreads();
  }

  // output: token 0 row, fp32
  if (tid < 64) {
    *(f32x4*)(out + (size_t)node * DIM + tid * 4) = *(const f32x4*)&xf[0][tid * 4];
  }
}

extern "C" void kernel_launch(void* const* d_in, const int* in_sizes, int n_in,
                              void* d_out, int out_size, void* d_ws, size_t ws_size,
                              hipStream_t stream) {
  (void)in_sizes; (void)n_in; (void)out_size; (void)ws_size;
  const float* h   = (const float*)d_in[0];
  const float* e   = (const float*)d_in[1];
  const int* src   = (const int*)d_in[2];
  const float* inw = (const float*)d_in[3];
  const float* inb = (const float*)d_in[4];
  const float* ow  = (const float*)d_in[5];
  const float* obi = (const float*)d_in[6];
  const float* f1w = (const float*)d_in[7];
  const float* f1b = (const float*)d_in[8];
  const float* f2w = (const float*)d_in[9];
  const float* f2b = (const float*)d_in[10];
  const float* l1g = (const float*)d_in[11];
  const float* l1b = (const float*)d_in[12];
  const float* l2g = (const float*)d_in[13];
  const float* l2b = (const float*)d_in[14];
  bf16* ws = (bf16*)d_ws;  // needs WTOT*2 = 2,359,296 bytes

  cvtw<<<1152, 256, 0, stream>>>(inw, ow, f1w, f2w, ws);
  nt_fused<<<20000, 512, 0, stream>>>(h, e, src, ws, inb, obi, f1b, f2b,
                                      l1g, l1b, l2g, l2b, (float*)d_out);
}